// Round 2
// baseline (1338.103 us; speedup 1.0000x reference)
//
#include <hip/hip_runtime.h>

#define ZN 131072          // B*H*W rows
#define DD 64              // embedding dim
#define KK 1024            // codebook entries
#define BSTRIDE 262144     // 64*64*64 (per-batch stride in z)
#define DSTRIDE 4096       // per-d stride in z (H*W)
#define ZQ_ELEMS 8388608   // 32*64*64*64

// ---- workspace layout ----
// [0,8)               double   loss accumulator
// [8,12)              unsigned flagged-row count
// [16,4112)           float    csq32[1024]   (numpy-emulated fp32)
// [4112,528400)       float    zsq32[131072] (numpy-emulated fp32)
// [528400,1052688)    int      worklist[131072]
#define WS_CSQ_OFF   16
#define WS_ZSQ_OFF   4112
#define WS_WORK_OFF  528400

// Emulate numpy pairwise fp32 sum for n=64 (8 strided accumulators + tree).
// a[i] must already be the fp32 values numpy would sum.
__device__ __forceinline__ float np_sum64(const float* a) {
    float r0 = a[0], r1 = a[1], r2 = a[2], r3 = a[3];
    float r4 = a[4], r5 = a[5], r6 = a[6], r7 = a[7];
#pragma unroll
    for (int i = 8; i < 64; i += 8) {
        r0 = __fadd_rn(r0, a[i + 0]); r1 = __fadd_rn(r1, a[i + 1]);
        r2 = __fadd_rn(r2, a[i + 2]); r3 = __fadd_rn(r3, a[i + 3]);
        r4 = __fadd_rn(r4, a[i + 4]); r5 = __fadd_rn(r5, a[i + 5]);
        r6 = __fadd_rn(r6, a[i + 6]); r7 = __fadd_rn(r7, a[i + 7]);
    }
    return __fadd_rn(__fadd_rn(__fadd_rn(r0, r1), __fadd_rn(r2, r3)),
                     __fadd_rn(__fadd_rn(r4, r5), __fadd_rn(r6, r7)));
}

// -------- csq32[k] = numpy-emulated fp32 sum of cb[k][d]^2 --------
__global__ __launch_bounds__(256) void vq_csq(const float* __restrict__ cb,
                                              float* __restrict__ csq) {
    int k = blockIdx.x * 256 + threadIdx.x;
    const float* c = cb + k * DD;
    float q[DD];
#pragma unroll
    for (int d = 0; d < DD; ++d) q[d] = __fmul_rn(c[d], c[d]);
    csq[k] = np_sum64(q);
}

// -------- fp32 prefilter argmin: one thread per row --------
__global__ __launch_bounds__(256) void vq_argmin(const float* __restrict__ z,
                                                 const float* __restrict__ cb,
                                                 const float* __restrict__ csq,
                                                 float* __restrict__ zsq32,
                                                 float* __restrict__ idxf_out,
                                                 unsigned* __restrict__ count,
                                                 int* __restrict__ worklist) {
    int n = blockIdx.x * 256 + threadIdx.x;
    int b = n >> 12;
    int p = n & 4095;
    const float* zp = z + (size_t)b * BSTRIDE + p;

    float zr[DD];
#pragma unroll
    for (int d = 0; d < DD; ++d) zr[d] = zp[(size_t)d * DSTRIDE];  // coalesced

    // numpy-emulated fp32 ||z||^2 (z_flat inner axis order == d order)
    {
        float q[DD];
#pragma unroll
        for (int d = 0; d < DD; ++d) q[d] = __fmul_rn(zr[d], zr[d]);
        zsq32[n] = np_sum64(q);
    }

    float min1 = 3.4e38f, min2 = 3.4e38f;
    int best = 0;
    for (int k = 0; k < KK; ++k) {
        const float* c = cb + k * DD;  // wave-uniform -> scalar loads
        float d0 = 0.f, d1 = 0.f, d2 = 0.f, d3 = 0.f;
#pragma unroll
        for (int d = 0; d < DD; d += 4) {
            d0 = fmaf(zr[d + 0], c[d + 0], d0);
            d1 = fmaf(zr[d + 1], c[d + 1], d1);
            d2 = fmaf(zr[d + 2], c[d + 2], d2);
            d3 = fmaf(zr[d + 3], c[d + 3], d3);
        }
        float dot = (d0 + d1) + (d2 + d3);
        float dist = fmaf(-2.f, dot, csq[k]);  // row-constant ||z||^2 dropped
        bool lt = dist < min1;                 // strict: keeps lowest k on ties
        float old1 = min1;
        min1 = lt ? dist : min1;
        min2 = lt ? old1 : fminf(min2, dist);
        best = lt ? k : best;
    }

    idxf_out[n] = (float)best;
    // Reference fp32 rounding noise can only flip ranking if true gap < ~1.6e-5.
    // Flag with 12x margin; flagged rows get exact reference-arithmetic emulation.
    if (min2 - min1 < 2e-4f) {
        unsigned w = atomicAdd(count, 1u);
        worklist[w] = n;
    }
}

// -------- reference-fp32-emulated argmin for flagged rows: block per row ----
__global__ __launch_bounds__(256) void vq_refine(const float* __restrict__ z,
                                                 const float* __restrict__ cb,
                                                 const float* __restrict__ csq,
                                                 const float* __restrict__ zsq32,
                                                 const unsigned* __restrict__ count,
                                                 const int* __restrict__ worklist,
                                                 float* __restrict__ idxf_out) {
    __shared__ float zrow[DD];
    __shared__ float bd[256];
    __shared__ int bi[256];
    unsigned cnt = *count;
    for (unsigned w = blockIdx.x; w < cnt; w += gridDim.x) {
        int n = worklist[w];
        int b = n >> 12;
        int p = n & 4095;
        __syncthreads();  // protect zrow across worklist iterations
        if (threadIdx.x < DD)
            zrow[threadIdx.x] = z[(size_t)b * BSTRIDE + (size_t)threadIdx.x * DSTRIDE + p];
        __syncthreads();

        float zsq = zsq32[n];
        float bestd = 3.4e38f;
        int bestk = KK;
#pragma unroll
        for (int j = 0; j < KK / 256; ++j) {
            int k = j * 256 + threadIdx.x;  // ascending within thread
            const float* c = cb + k * DD;
            double dot = 0.0;
#pragma unroll
            for (int d = 0; d < DD; ++d)
                dot = fma((double)zrow[d], (double)c[d], dot);
            // emulate: fl32(2*C_sgemm) ~= fl32(2*exact_dot)
            float twoC = (float)(2.0 * dot);
            float s = __fadd_rn(zsq, csq[k]);       // fl32(zsq + csq)
            float dist = __fsub_rn(s, twoC);        // fl32(s - 2C)
            if (dist < bestd) { bestd = dist; bestk = k; }  // first-occurrence
        }
        bd[threadIdx.x] = bestd;
        bi[threadIdx.x] = bestk;
        __syncthreads();
        for (int off = 128; off; off >>= 1) {
            if (threadIdx.x < (unsigned)off) {
                float od = bd[threadIdx.x + off];
                int oi = bi[threadIdx.x + off];
                if (od < bd[threadIdx.x] ||
                    (od == bd[threadIdx.x] && oi < bi[threadIdx.x])) {
                    bd[threadIdx.x] = od;
                    bi[threadIdx.x] = oi;
                }
            }
            __syncthreads();
        }
        if (threadIdx.x == 0) idxf_out[n] = (float)bi[0];
    }
}

// -------- gather z_q + fused loss partial reduction --------
__global__ __launch_bounds__(256) void vq_gather_loss(const float* __restrict__ z,
                                                      const float* __restrict__ cb,
                                                      const float* __restrict__ idxf,
                                                      float* __restrict__ zq_out,
                                                      double* __restrict__ acc) {
    int n = blockIdx.x * 256 + threadIdx.x;
    int b = n >> 12;
    int p = n & 4095;
    const float* zp = z + (size_t)b * BSTRIDE + p;
    float* qp = zq_out + (size_t)b * BSTRIDE + p;
    int k = (int)idxf[n];
    const float* c = cb + k * DD;

    float s = 0.f;
#pragma unroll
    for (int d = 0; d < DD; ++d) {
        float q = c[d];
        float diff = q - zp[(size_t)d * DSTRIDE];
        s = fmaf(diff, diff, s);
        qp[(size_t)d * DSTRIDE] = q;  // z_q_st == z_q numerically
    }

#pragma unroll
    for (int off = 32; off; off >>= 1) s += __shfl_down(s, off, 64);
    __shared__ float partial[4];
    if ((threadIdx.x & 63) == 0) partial[threadIdx.x >> 6] = s;
    __syncthreads();
    if (threadIdx.x == 0) {
        float t = (partial[0] + partial[1]) + (partial[2] + partial[3]);
        atomicAdd(acc, (double)t);
    }
}

__global__ void vq_finalize(const double* __restrict__ acc, float* __restrict__ loss_out) {
    *loss_out = (float)(1.25 * (*acc) / (double)ZQ_ELEMS);
}

extern "C" void kernel_launch(void* const* d_in, const int* in_sizes, int n_in,
                              void* d_out, int out_size, void* d_ws, size_t ws_size,
                              hipStream_t stream) {
    const float* z = (const float*)d_in[0];
    const float* cb = (const float*)d_in[1];
    float* out = (float*)d_out;

    float* zq_out = out;                   // [0, 8388608)
    float* loss_out = out + ZQ_ELEMS;      // [8388608]
    float* idxf_out = out + ZQ_ELEMS + 1;  // [8388609, +131072)

    char* ws = (char*)d_ws;
    double* acc = (double*)ws;
    unsigned* count = (unsigned*)(ws + 8);
    float* csq = (float*)(ws + WS_CSQ_OFF);
    float* zsq32 = (float*)(ws + WS_ZSQ_OFF);
    int* worklist = (int*)(ws + WS_WORK_OFF);

    hipMemsetAsync(d_ws, 0, 16, stream);  // acc=0, count=0

    vq_csq<<<KK / 256, 256, 0, stream>>>(cb, csq);
    vq_argmin<<<ZN / 256, 256, 0, stream>>>(z, cb, csq, zsq32, idxf_out, count, worklist);
    vq_refine<<<1024, 256, 0, stream>>>(z, cb, csq, zsq32, count, worklist, idxf_out);
    vq_gather_loss<<<ZN / 256, 256, 0, stream>>>(z, cb, idxf_out, zq_out, acc);
    vq_finalize<<<1, 1, 0, stream>>>(acc, loss_out);
}

// Round 3
// 866.969 us; speedup vs baseline: 1.5434x; 1.5434x over previous
//
#include <hip/hip_runtime.h>

#define ZN 131072          // B*H*W rows
#define DD 64              // embedding dim
#define KK 1024            // codebook entries
#define BSTRIDE 262144     // 64*64*64 (per-batch stride in z)
#define DSTRIDE 4096       // per-d stride in z (H*W)
#define ZQ_ELEMS 8388608   // 32*64*64*64

// ---- workspace layout ----
// [0,8)                double   loss accumulator
// [8,12)               unsigned flagged-row count
// [16,4112)            float    csq32[1024]    (numpy-emulated fp32)
// [4112,528400)        float    zsq32[131072]  (numpy-emulated fp32)
// [528400,1052688)     int      worklist[131072]
// [1052688,2101264)    u64      pack[131072]   (ordered_dist<<32 | k)
// [2101264,2363408)    float    cbT[64][1024]  (transposed codebook)
#define WS_CSQ_OFF   16
#define WS_ZSQ_OFF   4112
#define WS_WORK_OFF  528400
#define WS_PACK_OFF  1052688
#define WS_CBT_OFF   2101264

// numpy-emulated fp32 sum of a[i]^2 over 64 elems: elementwise fp32 square,
// then pairwise sum (8 strided accumulators + tree) — matches np.sum(x*x).
__device__ __forceinline__ float np_sumsq64(const float* a) {
    float r0 = __fmul_rn(a[0], a[0]), r1 = __fmul_rn(a[1], a[1]);
    float r2 = __fmul_rn(a[2], a[2]), r3 = __fmul_rn(a[3], a[3]);
    float r4 = __fmul_rn(a[4], a[4]), r5 = __fmul_rn(a[5], a[5]);
    float r6 = __fmul_rn(a[6], a[6]), r7 = __fmul_rn(a[7], a[7]);
#pragma unroll
    for (int i = 8; i < 64; i += 8) {
        r0 = __fadd_rn(r0, __fmul_rn(a[i + 0], a[i + 0]));
        r1 = __fadd_rn(r1, __fmul_rn(a[i + 1], a[i + 1]));
        r2 = __fadd_rn(r2, __fmul_rn(a[i + 2], a[i + 2]));
        r3 = __fadd_rn(r3, __fmul_rn(a[i + 3], a[i + 3]));
        r4 = __fadd_rn(r4, __fmul_rn(a[i + 4], a[i + 4]));
        r5 = __fadd_rn(r5, __fmul_rn(a[i + 5], a[i + 5]));
        r6 = __fadd_rn(r6, __fmul_rn(a[i + 6], a[i + 6]));
        r7 = __fadd_rn(r7, __fmul_rn(a[i + 7], a[i + 7]));
    }
    return __fadd_rn(__fadd_rn(__fadd_rn(r0, r1), __fadd_rn(r2, r3)),
                     __fadd_rn(__fadd_rn(r4, r5), __fadd_rn(r6, r7)));
}

__global__ __launch_bounds__(256) void vq_csq(const float* __restrict__ cb,
                                              float* __restrict__ csq) {
    int k = blockIdx.x * 256 + threadIdx.x;
    csq[k] = np_sumsq64(cb + k * DD);
}

// cbT[d][k] = cb[k][d]
__global__ __launch_bounds__(256) void vq_transpose(const float* __restrict__ cb,
                                                    float* __restrict__ cbT) {
    int i = blockIdx.x * 256 + threadIdx.x;  // i = d*1024 + k
    int d = i >> 10, k = i & 1023;
    cbT[i] = cb[k * DD + d];
}

// -------- fp32 prefilter argmin: 2 rows per thread --------
__global__ __launch_bounds__(256) void vq_argmin(const float* __restrict__ z,
                                                 const float* __restrict__ cb,
                                                 const float* __restrict__ csq,
                                                 float* __restrict__ zsq32,
                                                 float* __restrict__ idxf_out,
                                                 unsigned* __restrict__ count,
                                                 int* __restrict__ worklist) {
    int n0 = blockIdx.x * 512 + threadIdx.x;
    int n1 = n0 + 256;
    int b0 = n0 >> 12, p0 = n0 & 4095;
    int b1 = n1 >> 12, p1 = n1 & 4095;
    const float* zp0 = z + (size_t)b0 * BSTRIDE + p0;
    const float* zp1 = z + (size_t)b1 * BSTRIDE + p1;

    float zr0[DD], zr1[DD];
#pragma unroll
    for (int d = 0; d < DD; ++d) zr0[d] = zp0[(size_t)d * DSTRIDE];  // coalesced
#pragma unroll
    for (int d = 0; d < DD; ++d) zr1[d] = zp1[(size_t)d * DSTRIDE];

    zsq32[n0] = np_sumsq64(zr0);
    zsq32[n1] = np_sumsq64(zr1);

    float amin1 = 3.4e38f, amin2 = 3.4e38f;
    float bmin1 = 3.4e38f, bmin2 = 3.4e38f;
    int abest = 0, bbest = 0;
    for (int k = 0; k < KK; ++k) {
        const float* c = cb + k * DD;  // wave-uniform -> scalar loads
        float a0 = 0.f, a1 = 0.f, a2 = 0.f, a3 = 0.f;
        float c0 = 0.f, c1 = 0.f, c2 = 0.f, c3 = 0.f;
#pragma unroll
        for (int d = 0; d < DD; d += 4) {
            float v0 = c[d + 0], v1 = c[d + 1], v2 = c[d + 2], v3 = c[d + 3];
            a0 = fmaf(zr0[d + 0], v0, a0);
            a1 = fmaf(zr0[d + 1], v1, a1);
            a2 = fmaf(zr0[d + 2], v2, a2);
            a3 = fmaf(zr0[d + 3], v3, a3);
            c0 = fmaf(zr1[d + 0], v0, c0);
            c1 = fmaf(zr1[d + 1], v1, c1);
            c2 = fmaf(zr1[d + 2], v2, c2);
            c3 = fmaf(zr1[d + 3], v3, c3);
        }
        float cs = csq[k];
        float dist0 = fmaf(-2.f, (a0 + a1) + (a2 + a3), cs);
        float dist1 = fmaf(-2.f, (c0 + c1) + (c2 + c3), cs);
        bool lt0 = dist0 < amin1;
        float o0 = amin1;
        amin1 = lt0 ? dist0 : amin1;
        amin2 = lt0 ? o0 : fminf(amin2, dist0);
        abest = lt0 ? k : abest;
        bool lt1 = dist1 < bmin1;
        float o1 = bmin1;
        bmin1 = lt1 ? dist1 : bmin1;
        bmin2 = lt1 ? o1 : fminf(bmin2, dist1);
        bbest = lt1 ? k : bbest;
    }

    idxf_out[n0] = (float)abest;
    idxf_out[n1] = (float)bbest;
    // fp32 rounding noise in the reference can only flip ranking for tiny gaps;
    // flag with wide margin — flagged rows get exact reference-arithmetic emulation.
    if (amin2 - amin1 < 2e-4f) worklist[atomicAdd(count, 1u)] = n0;
    if (bmin2 - bmin1 < 2e-4f) worklist[atomicAdd(count, 1u)] = n1;
}

// -------- reference-fp32-emulated argmin for flagged rows --------
// work item = (flagged row r, code k); lanes <-> consecutive k (coalesced cbT);
// each wave = 64 k's of one row -> shuffle-min -> one atomicMin per wave.
__global__ __launch_bounds__(256) void vq_refine(const float* __restrict__ z,
                                                 const float* __restrict__ cbT,
                                                 const float* __restrict__ csq,
                                                 const float* __restrict__ zsq32,
                                                 const unsigned* __restrict__ count,
                                                 const int* __restrict__ worklist,
                                                 unsigned long long* __restrict__ pack) {
    unsigned cnt = *count;
    unsigned long long total = (unsigned long long)cnt << 10;
    unsigned long long stride = (unsigned long long)gridDim.x * 256;
    for (unsigned long long w = blockIdx.x * 256 + threadIdx.x; w < total; w += stride) {
        unsigned r = (unsigned)(w >> 10);
        unsigned k = (unsigned)(w & 1023);
        int n = worklist[r];
        int b = n >> 12, p = n & 4095;
        const float* zp = z + (size_t)b * BSTRIDE + p;

        double a0 = 0.0, a1 = 0.0, a2 = 0.0, a3 = 0.0;
#pragma unroll
        for (int d = 0; d < DD; d += 4) {
            a0 = fma((double)zp[(size_t)(d + 0) * DSTRIDE], (double)cbT[(d + 0) * KK + k], a0);
            a1 = fma((double)zp[(size_t)(d + 1) * DSTRIDE], (double)cbT[(d + 1) * KK + k], a1);
            a2 = fma((double)zp[(size_t)(d + 2) * DSTRIDE], (double)cbT[(d + 2) * KK + k], a2);
            a3 = fma((double)zp[(size_t)(d + 3) * DSTRIDE], (double)cbT[(d + 3) * KK + k], a3);
        }
        double dot = (a0 + a1) + (a2 + a3);
        float twoC = (float)(2.0 * dot);               // ~sgemm output, correctly rounded
        float dist = __fsub_rn(__fadd_rn(zsq32[n], csq[k]), twoC);  // reference fp32 ops

        unsigned ub = __float_as_uint(dist);
        ub = (ub & 0x80000000u) ? ~ub : (ub | 0x80000000u);  // order-preserving map
        unsigned long long pk = ((unsigned long long)ub << 32) | k;  // ties -> lowest k
#pragma unroll
        for (int off = 32; off; off >>= 1) {
            unsigned long long o = (unsigned long long)__shfl_xor((long long)pk, off, 64);
            pk = pk < o ? pk : o;
        }
        if ((threadIdx.x & 63) == 0) atomicMin(&pack[r], pk);
    }
}

__global__ __launch_bounds__(256) void vq_writeback(const unsigned* __restrict__ count,
                                                    const int* __restrict__ worklist,
                                                    const unsigned long long* __restrict__ pack,
                                                    float* __restrict__ idxf_out) {
    unsigned i = blockIdx.x * 256 + threadIdx.x;
    if (i < *count)
        idxf_out[worklist[i]] = (float)(unsigned)(pack[i] & 0xFFFFFFFFull);
}

// -------- gather z_q + fused loss partial reduction --------
__global__ __launch_bounds__(256) void vq_gather_loss(const float* __restrict__ z,
                                                      const float* __restrict__ cb,
                                                      const float* __restrict__ idxf,
                                                      float* __restrict__ zq_out,
                                                      double* __restrict__ acc) {
    int n = blockIdx.x * 256 + threadIdx.x;
    int b = n >> 12, p = n & 4095;
    const float* zp = z + (size_t)b * BSTRIDE + p;
    float* qp = zq_out + (size_t)b * BSTRIDE + p;
    int k = (int)idxf[n];
    const float* c = cb + k * DD;

    float s = 0.f;
#pragma unroll
    for (int d = 0; d < DD; ++d) {
        float q = c[d];
        float diff = q - zp[(size_t)d * DSTRIDE];
        s = fmaf(diff, diff, s);
        qp[(size_t)d * DSTRIDE] = q;  // z_q_st == z_q numerically
    }

#pragma unroll
    for (int off = 32; off; off >>= 1) s += __shfl_down(s, off, 64);
    __shared__ float partial[4];
    if ((threadIdx.x & 63) == 0) partial[threadIdx.x >> 6] = s;
    __syncthreads();
    if (threadIdx.x == 0) {
        float t = (partial[0] + partial[1]) + (partial[2] + partial[3]);
        atomicAdd(acc, (double)t);
    }
}

__global__ void vq_finalize(const double* __restrict__ acc, float* __restrict__ loss_out) {
    *loss_out = (float)(1.25 * (*acc) / (double)ZQ_ELEMS);
}

extern "C" void kernel_launch(void* const* d_in, const int* in_sizes, int n_in,
                              void* d_out, int out_size, void* d_ws, size_t ws_size,
                              hipStream_t stream) {
    const float* z = (const float*)d_in[0];
    const float* cb = (const float*)d_in[1];
    float* out = (float*)d_out;

    float* zq_out = out;                   // [0, 8388608)
    float* loss_out = out + ZQ_ELEMS;      // [8388608]
    float* idxf_out = out + ZQ_ELEMS + 1;  // [8388609, +131072)

    char* ws = (char*)d_ws;
    double* acc = (double*)ws;
    unsigned* count = (unsigned*)(ws + 8);
    float* csq = (float*)(ws + WS_CSQ_OFF);
    float* zsq32 = (float*)(ws + WS_ZSQ_OFF);
    int* worklist = (int*)(ws + WS_WORK_OFF);
    unsigned long long* pack = (unsigned long long*)(ws + WS_PACK_OFF);
    float* cbT = (float*)(ws + WS_CBT_OFF);

    hipMemsetAsync(d_ws, 0, 16, stream);                        // acc=0, count=0
    hipMemsetAsync(ws + WS_PACK_OFF, 0xFF, ZN * 8, stream);     // pack = UINT64_MAX

    vq_csq<<<KK / 256, 256, 0, stream>>>(cb, csq);
    vq_transpose<<<KK * DD / 256, 256, 0, stream>>>(cb, cbT);
    vq_argmin<<<ZN / 512, 256, 0, stream>>>(z, cb, csq, zsq32, idxf_out, count, worklist);
    vq_refine<<<2048, 256, 0, stream>>>(z, cbT, csq, zsq32, count, worklist, pack);
    vq_writeback<<<ZN / 256, 256, 0, stream>>>(count, worklist, pack, idxf_out);
    vq_gather_loss<<<ZN / 256, 256, 0, stream>>>(z, cb, idxf_out, zq_out, acc);
    vq_finalize<<<1, 1, 0, stream>>>(acc, loss_out);
}